// Round 1
// baseline (746.636 us; speedup 1.0000x reference)
//
#include <hip/hip_runtime.h>
#include <cstdint>

#define HIDDEN 128
#define MTOT 16

// ---------------------------------------------------------------------------
// q/k projection: out[r][j] = scale * sum_d x[r][d] * W[j][d]
// W staged in LDS (64KB) with XOR swizzle for conflict-free column reads.
// Each thread owns one output column; x row values broadcast via float4 loads.
// ---------------------------------------------------------------------------
__global__ __launch_bounds__(256) void proj_kernel(
    const float* __restrict__ x, const float* __restrict__ W,
    float* __restrict__ out, int n_rows, float scale) {
  __shared__ float sW[128 * 128];  // 64 KB, XOR-swizzled layout
  for (int i = threadIdx.x; i < 128 * 128; i += 256) {
    int j = i >> 7, d = i & 127;
    sW[j * 128 + (d ^ (j & 31))] = W[i] * scale;
  }
  __syncthreads();

  const int col  = threadIdx.x & 127;
  const int rpar = threadIdx.x >> 7;  // 0 or 1: even/odd rows
  const int cx   = col & 31;
  const float* sWc = sW + col * 128;

  int row0 = blockIdx.x * 64;
  int rend = min(row0 + 64, n_rows);
  for (int r = row0 + rpar; r < rend; r += 2) {
    const float4* xr = (const float4*)(x + (size_t)r * HIDDEN);
    float a0 = 0.f, a1 = 0.f, a2 = 0.f, a3 = 0.f;
#pragma unroll
    for (int d4 = 0; d4 < 32; ++d4) {
      float4 xv = xr[d4];  // broadcast across wave (all lanes same row)
      int d = d4 * 4;
      a0 += xv.x * sWc[(d + 0) ^ cx];
      a1 += xv.y * sWc[(d + 1) ^ cx];
      a2 += xv.z * sWc[(d + 2) ^ cx];
      a3 += xv.w * sWc[(d + 3) ^ cx];
    }
    out[(size_t)r * HIDDEN + col] = (a0 + a1) + (a2 + a3);
  }
}

// ---------------------------------------------------------------------------
// Edge kernel: 32 lanes per edge. Lane i covers dims 4i..4i+3.
// Head h = lane/8 (8 lanes * 4 dims = 32 dims per head).
// shfl_xor(1,2,4) reduces within each 8-lane head group.
// Lanes 0..15 scatter the 16 spherical components (head-of-m via compares).
// ---------------------------------------------------------------------------
__global__ __launch_bounds__(256) void edge_kernel(
    const float* __restrict__ q, const float* __restrict__ k,
    const float* __restrict__ w_ij, const float* __restrict__ sph,
    const int* __restrict__ ei, const float* __restrict__ cutoff,
    float* __restrict__ out, int E, int ngroups) {
  const int g0       = blockIdx.x * 8 + (threadIdx.x >> 5);
  const int lane     = threadIdx.x & 31;
  const int halfbase = threadIdx.x & 32;  // which 32-lane group of the wave
  // m -> head: m0->h0, m1..3->h1, m4..8->h2, m9..15->h3
  const int h_for_m  = (lane >= 1) + (lane >= 4) + (lane >= 9);
  const int srcLane  = halfbase + (h_for_m << 3);

  for (int e = g0; e < E; e += ngroups) {
    int src = ei[e];
    int dst = ei[E + e];
    float4 w4 = ((const float4*)(w_ij + (size_t)e * HIDDEN))[lane];
    float4 q4 = ((const float4*)(q + (size_t)dst * HIDDEN))[lane];
    float4 k4 = ((const float4*)(k + (size_t)src * HIDDEN))[lane];
    float p = q4.x * w4.x * k4.x + q4.y * w4.y * k4.y +
              q4.z * w4.z * k4.z + q4.w * w4.w * k4.w;
    p += __shfl_xor(p, 1);
    p += __shfl_xor(p, 2);
    p += __shfl_xor(p, 4);
    // all 8 lanes of head group h now hold alpha_raw[h] (scale folded into q)
    float alpha = p * cutoff[e];
    float am = __shfl(alpha, srcLane);  // fetch the head this m needs
    if (lane < 16) {
      atomicAdd(out + (size_t)dst * MTOT + lane,
                am * sph[(size_t)e * MTOT + lane]);
    }
  }
}

extern "C" void kernel_launch(void* const* d_in, const int* in_sizes, int n_in,
                              void* d_out, int out_size, void* d_ws, size_t ws_size,
                              hipStream_t stream) {
  // inputs: chi, sph_ij, x, w_ij, edge_index, cutoff, Wq, Wk
  const float* sph    = (const float*)d_in[1];
  const float* x      = (const float*)d_in[2];
  const float* w_ij   = (const float*)d_in[3];
  const int*   ei     = (const int*)d_in[4];
  const float* cutoff = (const float*)d_in[5];
  const float* Wq     = (const float*)d_in[6];
  const float* Wk     = (const float*)d_in[7];
  float* out = (float*)d_out;

  const int n_nodes = in_sizes[0] / MTOT;  // chi is [N, 16]
  const int E       = in_sizes[5];         // cutoff is [E, 1]

  float* q = (float*)d_ws;
  float* k = q + (size_t)n_nodes * HIDDEN;

  hipMemsetAsync(d_out, 0, (size_t)out_size * sizeof(float), stream);

  const int pgrid = (n_nodes + 63) / 64;
  const float inv_sqrt_hd = 0.17677669529663687f;  // 1/sqrt(32)
  proj_kernel<<<pgrid, 256, 0, stream>>>(x, Wq, q, n_nodes, inv_sqrt_hd);
  proj_kernel<<<pgrid, 256, 0, stream>>>(x, Wk, k, n_nodes, 1.0f);

  const int NB = 20000;                  // 160000 groups -> exactly 10 edges each
  const int ngroups = NB * 8;
  edge_kernel<<<NB, 256, 0, stream>>>(q, k, w_ij, sph, ei, cutoff, out, E, ngroups);
}